// Round 1
// baseline (76.620 us; speedup 1.0000x reference)
//
#include <hip/hip_runtime.h>
#include <math.h>

#define HW_SZ 32768
#define C_SZ  256
#define L_SZ  5
#define CHW   (C_SZ * HW_SZ)     // 8,388,608 elements (int-safe)

typedef float vfloat4 __attribute__((ext_vector_type(4)));

// ---------------------------------------------------------------------------
// Two-pass fused kernel. Block = 512 threads (8 waves), owns 32 consecutive
// spatial locations n.
//   lane = 8*ci + ni4 ; thread's n-range = blk*32 + 4*ni4 .. +3 (one float4)
//   thread's channels: c = 32*wave + 8*j + ci, j = 0..3
// Pass 1: stream 20 float4 loads, accumulate dot partials s[k]/t[k] on the
//         fly (no data hold), store ego plane immediately (maskless) -> ego
//         writes overlap the global read phase.
// Reduce: shfl_xor butterfly over ci -> LDS cross-wave -> 32-thread
//         softmax/gate -> mask broadcast (identical math to v1, absmax 0).
// Pass 2: reload l=1..4 (L1/L2/L3-resident: block footprint just touched,
//         x fits in the 256 MB Infinity Cache) and store masked. Loads and
//         stores interleave -> continuous R/W mixing instead of a pure-read
//         phase followed by a pure-write phase.
// Register hold drops from ~112 live floats to ~50 -> launch_bounds(512,6)
// targets 3 blocks/CU (24 waves) instead of 2.
// HBM traffic: read 168 MB + write 168 MB (pass-2 reads served by caches).
// ---------------------------------------------------------------------------
__global__ __launch_bounds__(512, 6) void is_fused_kernel(
    const float* __restrict__ x,      // (L, C, HW)
    const float* __restrict__ mlp_w,  // (1, C)
    const float* __restrict__ mlp_b,  // (1,)
    float* __restrict__ out)          // (L, C, HW)
{
    __shared__ float w_sh[C_SZ];
    __shared__ float part[8][8][8][5];   // [wave][ni4][val k][n-comp], pad 4->5
    __shared__ float m_sh[32];

    const int tid  = threadIdx.x;
    const int wv   = tid >> 6;
    const int lane = tid & 63;
    const int ci   = lane >> 3;
    const int ni4  = lane & 7;
    const int n0   = blockIdx.x * 32 + ni4 * 4;

    if (tid < C_SZ) w_sh[tid] = mlp_w[tid];
    __syncthreads();

    const int cbase = 32 * wv + ci;          // + 8*j
    const float* bp = x   + cbase * HW_SZ + n0;
    float*       op = out + cbase * HW_SZ + n0;

    // ---- pass 1: stream loads, accumulate partial dots, store ego ----
    vfloat4 s[4] = {{0,0,0,0},{0,0,0,0},{0,0,0,0},{0,0,0,0}};
    vfloat4 t[4] = {{0,0,0,0},{0,0,0,0},{0,0,0,0},{0,0,0,0}};
    #pragma unroll
    for (int j = 0; j < 4; ++j) {
        const float wc = w_sh[cbase + 8 * j];
        const vfloat4 e  = *(const vfloat4*)(bp + j * 8 * HW_SZ);
        const vfloat4 v1 = *(const vfloat4*)(bp + 1 * CHW + j * 8 * HW_SZ);
        const vfloat4 v2 = *(const vfloat4*)(bp + 2 * CHW + j * 8 * HW_SZ);
        const vfloat4 v3 = *(const vfloat4*)(bp + 3 * CHW + j * 8 * HW_SZ);
        const vfloat4 v4 = *(const vfloat4*)(bp + 4 * CHW + j * 8 * HW_SZ);
        s[0] += e * v1;  t[0] += wc * v1;
        s[1] += e * v2;  t[1] += wc * v2;
        s[2] += e * v3;  t[2] += wc * v3;
        s[3] += e * v4;  t[3] += wc * v4;
        __builtin_nontemporal_store(e, (vfloat4*)(op + j * 8 * HW_SZ));
    }

    // ---- butterfly reduce over ci (lane xor 8,16,32) ----
    #pragma unroll
    for (int m = 8; m <= 32; m <<= 1) {
        #pragma unroll
        for (int k = 0; k < 4; ++k) {
            #pragma unroll
            for (int c = 0; c < 4; ++c) {
                s[k][c] += __shfl_xor(s[k][c], m, 64);
                t[k][c] += __shfl_xor(t[k][c], m, 64);
            }
        }
    }
    if (ci == 0) {
        #pragma unroll
        for (int k = 0; k < 4; ++k)
            #pragma unroll
            for (int c = 0; c < 4; ++c) {
                part[wv][ni4][k][c]     = s[k][c];
                part[wv][ni4][k + 4][c] = t[k][c];
            }
    }
    __syncthreads();

    // ---- cross-wave reduce + softmax + gate (32 threads, 1 per n) ----
    if (tid < 32) {
        const int g = tid >> 2, cc = tid & 3;
        float ss[4] = {0, 0, 0, 0}, tt[4] = {0, 0, 0, 0};
        #pragma unroll
        for (int w8 = 0; w8 < 8; ++w8) {
            #pragma unroll
            for (int k = 0; k < 4; ++k) {
                ss[k] += part[w8][g][k][cc];
                tt[k] += part[w8][g][k + 4][cc];
            }
        }
        const float scale = 0.0625f;   // 1/sqrt(256)
        #pragma unroll
        for (int k = 0; k < 4; ++k) ss[k] *= scale;

        const float smax = fmaxf(fmaxf(ss[0], ss[1]), fmaxf(ss[2], ss[3]));
        const float p0 = expf(ss[0] - smax);
        const float p1 = expf(ss[1] - smax);
        const float p2 = expf(ss[2] - smax);
        const float p3 = expf(ss[3] - smax);
        const float z  = (p0 * tt[0] + p1 * tt[1] + p2 * tt[2] + p3 * tt[3])
                         / ((p0 + p1) + (p2 + p3)) + mlp_b[0];
        // sigmoid(relu(z)) > 0.5  <=>  z > 0  (exact)
        m_sh[tid] = (z > 0.f) ? 1.f : 0.f;
    }
    __syncthreads();

    // ---- pass 2: reload l=1..4 (cache-hot), scale, store ----
    const int nl = ni4 * 4;
    vfloat4 m4;
    m4.x = m_sh[nl];     m4.y = m_sh[nl + 1];
    m4.z = m_sh[nl + 2]; m4.w = m_sh[nl + 3];

    #pragma unroll
    for (int l = 1; l < 5; ++l)
        #pragma unroll
        for (int j = 0; j < 4; ++j) {
            const vfloat4 vv = *(const vfloat4*)(bp + l * CHW + j * 8 * HW_SZ);
            __builtin_nontemporal_store(vv * m4,
                                        (vfloat4*)(op + l * CHW + j * 8 * HW_SZ));
        }
}

extern "C" void kernel_launch(void* const* d_in, const int* in_sizes, int n_in,
                              void* d_out, int out_size, void* d_ws, size_t ws_size,
                              hipStream_t stream) {
    const float* x = (const float*)d_in[0];   // node_feature (5,256,128,256)
    const float* w = (const float*)d_in[1];   // mlp_w (1,256)
    const float* b = (const float*)d_in[2];   // mlp_b (1,)
    float* out = (float*)d_out;

    hipLaunchKernelGGL(is_fused_kernel, dim3(HW_SZ / 32), dim3(512), 0, stream,
                       x, w, b, out);
}